// Round 1
// baseline (870.815 us; speedup 1.0000x reference)
//
#include <hip/hip_runtime.h>
#include <math.h>

#define B 512
#define FEAT 8
#define IN 9
#define R 32
#define NLAYERS 24
#define L 256
#define HID 128

#define SCAN_BLOCKS 128          // 4 samples per block (wave-per-sample)
#define COPY_BLOCKS 2048
#define ROWS (NLAYERS * B * R)   /* 393216 queue rows */
#define OUTQ_FLOATS (ROWS * 257) /* 101,056,512 floats (<2^31) */
#define NQ (OUTQ_FLOATS / 4)     /* 25,264,128 aligned float4 quanta */

__device__ __forceinline__ float sigmoidf_(float x) {
    return 1.0f / (1.0f + __expf(-x));
}
__device__ __forceinline__ float tanhf_(float x) {
    // tanh(x) = sign(x) * (1 - 2/(e^{2|x|}+1)); overflow-safe (exp->inf => 1)
    float a = __expf(2.0f * fabsf(x));
    float r = 1.0f - 2.0f / (a + 1.0f);
    return copysignf(r, x);
}

// ---------------------------------------------------------------------------
// Kernel 1: recurrent scan. One wave per batch sample. Writes h_hat (out[0..B))
// and the appended queue column h_seq -> outq[row*257 + 256].
// Math identical to the previously harness-verified kernel.
// ---------------------------------------------------------------------------
__global__ __launch_bounds__(256) void wavedec_scan(
    const float* __restrict__ x, const float* __restrict__ features,
    const float* __restrict__ queues,
    const float* __restrict__ fc_h_w, const float* __restrict__ fc_h_b,
    const float* __restrict__ fc_c_w, const float* __restrict__ fc_c_b,
    const float* __restrict__ conv_w, const float* __restrict__ conv_b,
    const float* __restrict__ fc1_w, const float* __restrict__ fc1_b,
    const float* __restrict__ fc2_w, const float* __restrict__ fc2_b,
    float* __restrict__ out)
{
    const int tid  = threadIdx.x;
    const int lane = tid & 63;
    const int wid  = tid >> 6;
    float* outq = out + B;   // update_queues region, rows of 257 floats

    const int b = blockIdx.x * 4 + wid;
    const int r = lane & 31;              // channel this lane owns (duplicated in upper half)
    __shared__ __align__(16) float sk[4][NLAYERS * R];   // skips per sample

    // input FC -> h0, c0
    float inp[IN];
    inp[0] = x[b];
    #pragma unroll
    for (int i = 0; i < FEAT; i++) inp[1 + i] = features[b * FEAT + i];
    float ah = fc_h_b[r], ac = fc_c_b[r];
    #pragma unroll
    for (int i = 0; i < IN; i++) {
        ah += inp[i] * fc_h_w[r * IN + i];
        ac += inp[i] * fc_c_w[r * IN + i];
    }
    float h = tanhf_(ah);
    float c = tanhf_(ac);

    for (int l = 0; l < NLAYERS; l++) {
        const int dil = 1 << (l & 7);
        const int base = (l * B + b) * R;           // queue row of (l,b,0)

        // appended column: h_seq[l] = input h of layer l
        if (lane < 32) outq[(long)(base + r) * 257 + 256] = h;

        // past activation p[r]
        float p = queues[(long)(base + r) * 256 + (256 - dil)];

        // out[j] = sum_r p[r]*W[j][r][0] + h[r]*W[j][r][1] + b[j]
        // lane computes j = lane and j = lane + 64
        const float* W0 = conv_w + ((long)l * 128 + lane) * 64;
        const float* W1 = W0 + 64 * 64;
        float acc0 = conv_b[l * 128 + lane];
        float acc1 = conv_b[l * 128 + lane + 64];
        #pragma unroll
        for (int rr = 0; rr < 32; rr += 2) {
            float4 wa = *(const float4*)(W0 + rr * 2);   // W[j][rr][0..1], W[j][rr+1][0..1]
            float4 wb = *(const float4*)(W1 + rr * 2);
            float h0v = __shfl(h, rr),     p0v = __shfl(p, rr);
            float h1v = __shfl(h, rr + 1), p1v = __shfl(p, rr + 1);
            acc0 += p0v * wa.x + h0v * wa.y + p1v * wa.z + h1v * wa.w;
            acc1 += p0v * wb.x + h0v * wb.y + p1v * wb.z + h1v * wb.w;
        }
        // lane r<32: ig = acc0 (j=r), cg = acc1 (j=64+r)
        // cf = out[32+r] = acc0 @ lane 32+r ; eg = out[96+r] = acc1 @ lane 32+r
        float cf = __shfl(acc0, r + 32);
        float eg = __shfl(acc1, r + 32);
        c = sigmoidf_(acc0) * c + tanhf_(cf) * sigmoidf_(acc1);
        h = sigmoidf_(eg) * tanhf_(c);

        if (lane < 32) sk[wid][l * R + r] = h;   // skips[l][b][r]
    }
    __syncthreads();

    // ---------------- head: y = relu(skips @ fc1_w.T + b1); out = y @ fc2_w.T + b2
    const float* w1a = fc1_w + (long)lane * 768;
    const float* w1b = fc1_w + (long)(lane + 64) * 768;
    const float* skp = sk[wid];
    float ya = fc1_b[lane], yb = fc1_b[lane + 64];
    for (int i = 0; i < 768; i += 4) {
        float4 s  = *(const float4*)(skp + i);
        float4 a4 = *(const float4*)(w1a + i);
        float4 b4 = *(const float4*)(w1b + i);
        ya += s.x * a4.x + s.y * a4.y + s.z * a4.z + s.w * a4.w;
        yb += s.x * b4.x + s.y * b4.y + s.z * b4.z + s.w * b4.w;
    }
    ya = fmaxf(ya, 0.0f);
    yb = fmaxf(yb, 0.0f);
    float v = ya * fc2_w[lane] + yb * fc2_w[lane + 64];
    #pragma unroll
    for (int off = 32; off; off >>= 1) v += __shfl_xor(v, off);
    if (lane == 0) out[b] = v + fc2_b[0];
}

// ---------------------------------------------------------------------------
// Kernel 2: output-driven queue copy. Every thread owns one aligned float4 of
// the 257-wide output region (grid-stride). Stores are 100% full-width,
// 16B-aligned, fully coalesced. Source element for output float o:
//   row = o / 257 (exact magic multiply), col = o - row*257
//   col < 256  -> queues[row*256 + col]  (== o - row, near-contiguous loads)
//   col == 256 -> read back h written by wavedec_scan (stream-ordered)
// ---------------------------------------------------------------------------
__global__ __launch_bounds__(256) void wavedec_copy(
    const float* __restrict__ queues, float* __restrict__ out)
{
    float* __restrict__ outq = out + B;
    const uint32_t stride = gridDim.x * blockDim.x;
    for (uint32_t q = blockIdx.x * blockDim.x + threadIdx.x; q < (uint32_t)NQ; q += stride) {
        const uint32_t o   = q << 2;
        const uint32_t row = (uint32_t)(((uint64_t)o * 4278255361ull) >> 40); // o/257 exact
        const uint32_t col = o - row * 257u;
        float v[4];
        #pragma unroll
        for (int i = 0; i < 4; i++) {
            uint32_t r2 = row, c2 = col + (uint32_t)i;
            if (c2 >= 257u) { r2 += 1u; c2 -= 257u; }
            // branchless pointer select: one scalar load either way
            const float* p = (c2 < 256u)
                ? (queues + (size_t)(r2 << 8) + c2)
                : (outq + (size_t)r2 * 257u + 256u);
            v[i] = *p;
        }
        *(float4*)(outq + (size_t)o) = make_float4(v[0], v[1], v[2], v[3]);
    }
}

extern "C" void kernel_launch(void* const* d_in, const int* in_sizes, int n_in,
                              void* d_out, int out_size, void* d_ws, size_t ws_size,
                              hipStream_t stream)
{
    const float* x        = (const float*)d_in[0];
    const float* features = (const float*)d_in[1];
    const float* queues   = (const float*)d_in[2];
    const float* fc_h_w   = (const float*)d_in[3];
    const float* fc_h_b   = (const float*)d_in[4];
    const float* fc_c_w   = (const float*)d_in[5];
    const float* fc_c_b   = (const float*)d_in[6];
    const float* conv_w   = (const float*)d_in[7];
    const float* conv_b   = (const float*)d_in[8];
    const float* fc1_w    = (const float*)d_in[9];
    const float* fc1_b    = (const float*)d_in[10];
    const float* fc2_w    = (const float*)d_in[11];
    const float* fc2_b    = (const float*)d_in[12];
    float* out = (float*)d_out;

    hipLaunchKernelGGL(wavedec_scan, dim3(SCAN_BLOCKS), dim3(256), 0, stream,
                       x, features, queues, fc_h_w, fc_h_b, fc_c_w, fc_c_b,
                       conv_w, conv_b, fc1_w, fc1_b, fc2_w, fc2_b, out);
    hipLaunchKernelGGL(wavedec_copy, dim3(COPY_BLOCKS), dim3(256), 0, stream,
                       queues, out);
}

// Round 2
// 794.452 us; speedup vs baseline: 1.0961x; 1.0961x over previous
//
#include <hip/hip_runtime.h>
#include <math.h>

#define B 512
#define FEAT 8
#define IN 9
#define R 32
#define NLAYERS 24
#define L 256
#define HID 128

#define SCAN_BLOCKS 128            // 4 samples per block (wave-per-sample)
#define COPY_BLOCKS 6144           // 4 waves/block x 4 groups/wave = 16 groups/block
#define ROWS (NLAYERS * B * R)     /* 393216 queue rows */
#define GROUPS (ROWS / 4)          /* 98304 4-row groups; 16 groups x 6144 blocks exact */

__device__ __forceinline__ float sigmoidf_(float x) {
    return 1.0f / (1.0f + __expf(-x));
}
__device__ __forceinline__ float tanhf_(float x) {
    // tanh(x) = sign(x) * (1 - 2/(e^{2|x|}+1)); overflow-safe (exp->inf => 1)
    float a = __expf(2.0f * fabsf(x));
    float r = 1.0f - 2.0f / (a + 1.0f);
    return copysignf(r, x);
}

// ---------------------------------------------------------------------------
// Merged kernel.
//   blocks [0, SCAN_BLOCKS): recurrent scan. Writes h_hat (out[0..B)) and the
//     appended queue column h_seq -> outq[row*257 + 256].  (verified math)
//   blocks [SCAN_BLOCKS, ...): queue copy. Writes cols [0,256) of every output
//     row; NEVER touches col 256 -> no ordering w.r.t. scan blocks needed.
//   Write sets are disjoint, so no inter-block sync of any kind is required.
//
// Copy decomposition: 4 consecutive rows = 1028 floats = 257 16B-aligned
// float4 quanta. Wave lane l stores quanta {l, 64+l, 128+l, 192+l} (fully
// coalesced 1KB per store instruction). Quanta 64/128/192 contain one col-256
// hole each -> lane 0 stores their other 3 floats scalar. Tail quantum 256
// (floats 1024..1027, hole at 1027) -> lane 1 stores 3 floats scalar.
// ---------------------------------------------------------------------------
__global__ __launch_bounds__(256) void wavedec_fused(
    const float* __restrict__ x, const float* __restrict__ features,
    const float* __restrict__ queues,
    const float* __restrict__ fc_h_w, const float* __restrict__ fc_h_b,
    const float* __restrict__ fc_c_w, const float* __restrict__ fc_c_b,
    const float* __restrict__ conv_w, const float* __restrict__ conv_b,
    const float* __restrict__ fc1_w, const float* __restrict__ fc1_b,
    const float* __restrict__ fc2_w, const float* __restrict__ fc2_b,
    float* __restrict__ out)
{
    const int tid  = threadIdx.x;
    const int lane = tid & 63;
    const int wid  = tid >> 6;
    float* outq = out + B;   // update_queues region, rows of 257 floats

    if (blockIdx.x >= SCAN_BLOCKS) {
        // ---------------- queue copy (cols 0..255 only) ------------------
        const int wv = (blockIdx.x - SCAN_BLOCKS) * 4 + wid;
        #pragma unroll
        for (int i = 0; i < 4; ++i) {
            const int g = wv * 4 + i;                      // 4-row group
            const float* __restrict__ src = queues + (size_t)g * 1024;
            float*       __restrict__ dst = outq   + (size_t)g * 1028;

            // k = 0: all lanes clean, 16B-aligned source
            {
                const float4 v = *(const float4*)(src + lane * 4);
                *(float4*)(dst + lane * 4) = v;
            }
            #pragma unroll
            for (int k = 1; k < 4; ++k) {
                const int f = (k * 64 + lane) * 4;         // output float offset in group
                if (lane == 0) {
                    // special quantum q = k*64: contains the col-256 hole
                    const int rig = k - 1;                 // row-in-group of first elem
                    const int c   = f - rig * 257;         // its column (254..256)
                    #pragma unroll
                    for (int j = 0; j < 4; ++j) {
                        const int cj = c + j;
                        if (cj == 256) continue;           // hole: scan writes it
                        const int s = f + j - rig - (cj > 256 ? 1 : 0);
                        dst[f + j] = src[s];
                    }
                } else {
                    const int s = f - k;                   // rig == k for lanes >= 1
                    const float v0 = src[s],     v1 = src[s + 1];
                    const float v2 = src[s + 2], v3 = src[s + 3];
                    *(float4*)(dst + f) = make_float4(v0, v1, v2, v3);
                }
            }
            // tail quantum q=256: floats 1024..1026 = row3 cols 253..255
            if (lane == 1) {
                dst[1024] = src[1021];
                dst[1025] = src[1022];
                dst[1026] = src[1023];
            }
        }
        return;
    }

    // ---------------- recurrent scan: one wave per batch sample ----------
    const int b = blockIdx.x * 4 + wid;
    const int r = lane & 31;              // channel this lane owns (duplicated in upper half)
    __shared__ __align__(16) float sk[4][NLAYERS * R];   // skips per sample

    // input FC -> h0, c0
    float inp[IN];
    inp[0] = x[b];
    #pragma unroll
    for (int i = 0; i < FEAT; i++) inp[1 + i] = features[b * FEAT + i];
    float ah = fc_h_b[r], ac = fc_c_b[r];
    #pragma unroll
    for (int i = 0; i < IN; i++) {
        ah += inp[i] * fc_h_w[r * IN + i];
        ac += inp[i] * fc_c_w[r * IN + i];
    }
    float h = tanhf_(ah);
    float c = tanhf_(ac);

    for (int l = 0; l < NLAYERS; l++) {
        const int dil = 1 << (l & 7);
        const int base = (l * B + b) * R;           // queue row of (l,b,0)

        // appended column: h_seq[l] = input h of layer l
        if (lane < 32) outq[(long)(base + r) * 257 + 256] = h;

        // past activation p[r]
        float p = queues[(long)(base + r) * 256 + (256 - dil)];

        // out[j] = sum_r p[r]*W[j][r][0] + h[r]*W[j][r][1] + b[j]
        // lane computes j = lane and j = lane + 64
        const float* W0 = conv_w + ((long)l * 128 + lane) * 64;
        const float* W1 = W0 + 64 * 64;
        float acc0 = conv_b[l * 128 + lane];
        float acc1 = conv_b[l * 128 + lane + 64];
        #pragma unroll
        for (int rr = 0; rr < 32; rr += 2) {
            float4 wa = *(const float4*)(W0 + rr * 2);   // W[j][rr][0..1], W[j][rr+1][0..1]
            float4 wb = *(const float4*)(W1 + rr * 2);
            float h0v = __shfl(h, rr),     p0v = __shfl(p, rr);
            float h1v = __shfl(h, rr + 1), p1v = __shfl(p, rr + 1);
            acc0 += p0v * wa.x + h0v * wa.y + p1v * wa.z + h1v * wa.w;
            acc1 += p0v * wb.x + h0v * wb.y + p1v * wb.z + h1v * wb.w;
        }
        // lane r<32: ig = acc0 (j=r), cg = acc1 (j=64+r)
        // cf = out[32+r] = acc0 @ lane 32+r ; eg = out[96+r] = acc1 @ lane 32+r
        float cf = __shfl(acc0, r + 32);
        float eg = __shfl(acc1, r + 32);
        c = sigmoidf_(acc0) * c + tanhf_(cf) * sigmoidf_(acc1);
        h = sigmoidf_(eg) * tanhf_(c);

        if (lane < 32) sk[wid][l * R + r] = h;   // skips[l][b][r]
    }
    __syncthreads();

    // ---------------- head: y = relu(skips @ fc1_w.T + b1); out = y @ fc2_w.T + b2
    const float* w1a = fc1_w + (long)lane * 768;
    const float* w1b = fc1_w + (long)(lane + 64) * 768;
    const float* skp = sk[wid];
    float ya = fc1_b[lane], yb = fc1_b[lane + 64];
    for (int i = 0; i < 768; i += 4) {
        float4 s  = *(const float4*)(skp + i);
        float4 a4 = *(const float4*)(w1a + i);
        float4 b4 = *(const float4*)(w1b + i);
        ya += s.x * a4.x + s.y * a4.y + s.z * a4.z + s.w * a4.w;
        yb += s.x * b4.x + s.y * b4.y + s.z * b4.z + s.w * b4.w;
    }
    ya = fmaxf(ya, 0.0f);
    yb = fmaxf(yb, 0.0f);
    float v = ya * fc2_w[lane] + yb * fc2_w[lane + 64];
    #pragma unroll
    for (int off = 32; off; off >>= 1) v += __shfl_xor(v, off);
    if (lane == 0) out[b] = v + fc2_b[0];
}

extern "C" void kernel_launch(void* const* d_in, const int* in_sizes, int n_in,
                              void* d_out, int out_size, void* d_ws, size_t ws_size,
                              hipStream_t stream)
{
    const float* x        = (const float*)d_in[0];
    const float* features = (const float*)d_in[1];
    const float* queues   = (const float*)d_in[2];
    const float* fc_h_w   = (const float*)d_in[3];
    const float* fc_h_b   = (const float*)d_in[4];
    const float* fc_c_w   = (const float*)d_in[5];
    const float* fc_c_b   = (const float*)d_in[6];
    const float* conv_w   = (const float*)d_in[7];
    const float* conv_b   = (const float*)d_in[8];
    const float* fc1_w    = (const float*)d_in[9];
    const float* fc1_b    = (const float*)d_in[10];
    const float* fc2_w    = (const float*)d_in[11];
    const float* fc2_b    = (const float*)d_in[12];
    float* out = (float*)d_out;

    hipLaunchKernelGGL(wavedec_fused, dim3(SCAN_BLOCKS + COPY_BLOCKS), dim3(256), 0, stream,
                       x, features, queues, fc_h_w, fc_h_b, fc_c_w, fc_c_b,
                       conv_w, conv_b, fc1_w, fc1_b, fc2_w, fc2_b, out);
}